// Round 7
// baseline (308.160 us; speedup 1.0000x reference)
//
#include <hip/hip_runtime.h>
#include <hip/hip_bf16.h>

// Self-attention, MODEL_DIM=1024, BATCH=4, SEQ=2048.
// R7: gemm256p rewritten with cross-phase ds_read prefetch (ds || MFMA
// overlap), register rotation (no LDS re-reads), 1 barrier/phase (4/K-tile),
// counted vmcnt at ph1/ph2 ends. QK-proj, scores(exp+rowsum), PV(/rowsum).
// VT on verified 128^2 kernel. zero_f32 folded into cast_w3.

typedef short bf16x8_t __attribute__((ext_vector_type(8)));
typedef float f32x4_t __attribute__((ext_vector_type(4)));
typedef unsigned short u16x8_t __attribute__((ext_vector_type(8)));

static __device__ __forceinline__ unsigned short f2bf(float f) {
  __hip_bfloat16 h = __float2bfloat16(f);
  return *reinterpret_cast<unsigned short*>(&h);
}

#define GLOAD_LDS16(gp, lp)                                            \
  __builtin_amdgcn_global_load_lds(                                    \
      (const __attribute__((address_space(1))) void*)(gp),             \
      (__attribute__((address_space(3))) void*)(lp), 16, 0, 0)

// ---------------------------------------------------------------------------
__global__ __launch_bounds__(256) void cast_f32_bf16(
    const float* __restrict__ in, unsigned short* __restrict__ out, int n8) {
  int i = blockIdx.x * 256 + threadIdx.x;
  if (i >= n8) return;
  float4 a = ((const float4*)in)[i * 2];
  float4 b = ((const float4*)in)[i * 2 + 1];
  u16x8_t o;
  o[0] = f2bf(a.x); o[1] = f2bf(a.y); o[2] = f2bf(a.z); o[3] = f2bf(a.w);
  o[4] = f2bf(b.x); o[5] = f2bf(b.y); o[6] = f2bf(b.z); o[7] = f2bf(b.w);
  ((u16x8_t*)out)[i] = o;
}

// Wq,Wk -> stacked Wqk; Wv -> Wvb; last blocks zero rowsum. One dispatch.
__global__ __launch_bounds__(256) void cast_w3(
    const float* __restrict__ Wq, const float* __restrict__ Wk,
    const float* __restrict__ Wv, unsigned short* __restrict__ Wqk,
    unsigned short* __restrict__ Wvb, float* __restrict__ rowsum) {
  int i = blockIdx.x * 256 + threadIdx.x;
  int seg = i >> 17;
  if (seg >= 3) {
    int l = i - 393216;
    if (l < 1024) {
      float4 z = {0.f, 0.f, 0.f, 0.f};
      ((float4*)rowsum)[l * 2] = z;
      ((float4*)rowsum)[l * 2 + 1] = z;
    }
    return;
  }
  int local = i & 131071;
  const float* src = (seg == 0) ? Wq : ((seg == 1) ? Wk : Wv);
  unsigned short* dst =
      (seg == 0) ? Wqk : ((seg == 1) ? (Wqk + 1048576) : Wvb);
  float4 a = ((const float4*)src)[local * 2];
  float4 b = ((const float4*)src)[local * 2 + 1];
  u16x8_t o;
  o[0] = f2bf(a.x); o[1] = f2bf(a.y); o[2] = f2bf(a.z); o[3] = f2bf(a.w);
  o[4] = f2bf(b.x); o[5] = f2bf(b.y); o[6] = f2bf(b.z); o[7] = f2bf(b.w);
  ((u16x8_t*)dst)[local] = o;
}

// ---------------------------------------------------------------------------
// 256 x BN NT bf16 GEMM, BK=64, 512 threads = 8 waves (2M x 4N).
// Software-pipelined 4-phase K-tile: each phase {barrier; prefetch next
// phase's ds_reads; issue one half-tile stage; MFMA cluster; [counted vmcnt]}.
// Register rotation afA/afB/bgY/bgX{0,1} -> zero LDS re-reads (24 b128/tile).
// Phases: ph0 (m0,n0) afA*bgX | read bgY(B_n1) | stage A_m1(t+1)
//         ph1 (m0,n1) afA*bgY | read afB(A_m1) | stage B_n0(t+1) | vmcnt(AL+BL)
//         ph2 (m1,n1) afB*bgY | read afA<-nx.A_m0(t+1) | stage A_m0(t+2) | vmcnt(AL)
//         ph3 (m1,n0) afB*bgX | read bgX'<-nx.B_n0(t+1) | stage B_n1(t+2)
// vmcnt invariant at ph0 entry: outstanding = {A_m0(t+1), B_n1(t+1)}.
// LDS chunk-XOR swizzled (phys = r*8 + (c8^(r&7))); bijective XCD swizzle.
// EPI 0: bf16(alpha*acc). 1: bf16(exp(alpha*acc)) + atomic rowsum.
// 2: f32 acc/rowsum[row].
template <int EPI, int BN>
__global__ __launch_bounds__(512, 2) void gemm256p(
    const unsigned short* __restrict__ A, const unsigned short* __restrict__ B,
    void* __restrict__ Cv, float* __restrict__ rowsum, int K, int lda,
    int ldb, int ldc, long long sA, long long sB, long long sC, float alpha,
    int rsz) {
  constexpr int NBG = BN / 64;  // bg frags per wave (4 / 2)
  constexpr int NH = NBG / 2;   // bg frags per phase (2 / 1)
  constexpr int BL = BN / 128;  // SB insts (2 / 1); SA insts AL = 2
  constexpr int BNW = BN / 4;   // wave n-extent (64 / 32)
  constexpr int ASZ = 256 * 64;
  constexpr int BSZ = BN * 64;

  __shared__ unsigned short lds[2][ASZ + BSZ];

  // T1: bijective XCD swizzle (nwg % 8 == 0 for all grids used)
  const int gx = gridDim.x, gy = gridDim.y;
  const int nwg = gx * gy * gridDim.z;
  const int orig = (blockIdx.z * gy + blockIdx.y) * gx + blockIdx.x;
  const int swz = (orig & 7) * (nwg >> 3) + (orig >> 3);
  const int bx = swz % gx;
  const int tmp = swz / gx;
  const int by = tmp % gy;
  const int z = tmp / gy;

  const int tid = threadIdx.x;
  const int lane = tid & 63;
  const int w = tid >> 6;
  const int wm = w >> 2, wn = w & 3;
  const int m0 = by * 256, n0 = bx * BN;

  A += (long long)z * sA;
  B += (long long)z * sB;

  // staging index tables (chunk l holds k-chunk (l&7)^(row&7))
  int sta_row[2][2], sta_col[2][2], sta_lds[2][2];
#pragma unroll
  for (int mh = 0; mh < 2; ++mh)
#pragma unroll
    for (int i = 0; i < 2; ++i) {
      int j = w * 2 + i;
      int l0 = (j >> 3) * 1024 + mh * 512 + (j & 7) * 64;
      int lf = l0 + lane;
      int R = lf >> 3;
      sta_row[mh][i] = R;
      sta_col[mh][i] = ((lf & 7) ^ (R & 7)) * 8;
      sta_lds[mh][i] = l0 * 8;
    }
  int stb_row[2][BL], stb_col[2][BL], stb_lds[2][BL];
#pragma unroll
  for (int nh = 0; nh < 2; ++nh)
#pragma unroll
    for (int i = 0; i < BL; ++i) {
      int l0;
      if (BL == 2) {
        int j = w * 2 + i;
        l0 = (j >> 2) * 512 + nh * 256 + (j & 3) * 64;
      } else {
        int j = w;
        l0 = (j >> 1) * 256 + nh * 128 + (j & 1) * 64;
      }
      int lf = l0 + lane;
      int R = lf >> 3;
      stb_row[nh][i] = R;
      stb_col[nh][i] = ((lf & 7) ^ (R & 7)) * 8;
      stb_lds[nh][i] = ASZ + l0 * 8;
    }

  // ds_read element offsets (K-invariant)
  const int q = lane >> 4, rl = lane & 15;
  int aoff[8][2], boff[NBG][2];
#pragma unroll
  for (int tt = 0; tt < 8; ++tt)
#pragma unroll
    for (int ks = 0; ks < 2; ++ks) {
      int ra = wm * 128 + tt * 16 + rl;
      aoff[tt][ks] = ra * 64 + (((ks * 4 + q) ^ (ra & 7)) * 8);
    }
#pragma unroll
  for (int u = 0; u < NBG; ++u)
#pragma unroll
    for (int ks = 0; ks < 2; ++ks) {
      int rb = wn * BNW + u * 16 + rl;
      boff[u][ks] = ASZ + rb * 64 + (((ks * 4 + q) ^ (rb & 7)) * 8);
    }

  f32x4_t acc[8][NBG];
#pragma unroll
  for (int i = 0; i < 8; ++i)
#pragma unroll
    for (int j = 0; j < NBG; ++j) acc[i][j] = (f32x4_t){0.f, 0.f, 0.f, 0.f};

  bf16x8_t afA[4][2], afB[4][2], bgY[NH][2], bgX0[NH][2], bgX1[NH][2];

#define SA(BUFI, MH, K0)                                                    \
  {                                                                         \
    _Pragma("unroll") for (int i_ = 0; i_ < 2; ++i_)                        \
        GLOAD_LDS16(&A[(long long)(m0 + sta_row[MH][i_]) * lda + (K0) +     \
                       sta_col[MH][i_]],                                    \
                    &lds[BUFI][sta_lds[MH][i_]]);                           \
  }
#define SB(BUFI, NH_, K0)                                                   \
  {                                                                         \
    _Pragma("unroll") for (int i_ = 0; i_ < BL; ++i_)                       \
        GLOAD_LDS16(&B[(long long)(n0 + stb_row[NH_][i_]) * ldb + (K0) +    \
                       stb_col[NH_][i_]],                                   \
                    &lds[BUFI][stb_lds[NH_][i_]]);                          \
  }
#define RD_AF(DST, L, MH)                                                   \
  _Pragma("unroll") for (int i_ = 0; i_ < 4; ++i_)                          \
  _Pragma("unroll") for (int ks_ = 0; ks_ < 2; ++ks_)                       \
      DST[i_][ks_] = *(const bf16x8_t*)&(L)[aoff[(MH)*4 + i_][ks_]];
#define RD_BG(DST, L, NH_)                                                  \
  _Pragma("unroll") for (int j_ = 0; j_ < NH; ++j_)                         \
  _Pragma("unroll") for (int ks_ = 0; ks_ < 2; ++ks_)                       \
      DST[j_][ks_] = *(const bf16x8_t*)&(L)[boff[(NH_)*NH + j_][ks_]];
#define MM(MH, NH_, AF, BG)                                                 \
  __builtin_amdgcn_sched_barrier(0);                                        \
  __builtin_amdgcn_s_setprio(1);                                            \
  _Pragma("unroll") for (int ks_ = 0; ks_ < 2; ++ks_)                       \
  _Pragma("unroll") for (int i_ = 0; i_ < 4; ++i_)                          \
  _Pragma("unroll") for (int j_ = 0; j_ < NH; ++j_)                         \
      acc[(MH)*4 + i_][(NH_)*NH + j_] =                                     \
          __builtin_amdgcn_mfma_f32_16x16x32_bf16(                          \
              AF[i_][ks_], BG[j_][ks_], acc[(MH)*4 + i_][(NH_)*NH + j_],    \
              0, 0, 0);                                                     \
  __builtin_amdgcn_s_setprio(0);

  // counted vmcnt helpers (literal immediates required)
#define VMC_PH1()                                                           \
  if constexpr (BL == 2) {                                                  \
    asm volatile("s_waitcnt vmcnt(4)" ::: "memory");                        \
  } else {                                                                  \
    asm volatile("s_waitcnt vmcnt(3)" ::: "memory");                        \
  }                                                                         \
  __builtin_amdgcn_sched_barrier(0);
#define VMC_PH2()                                                           \
  asm volatile("s_waitcnt vmcnt(2)" ::: "memory");                          \
  __builtin_amdgcn_sched_barrier(0);

#define TILE(T, BU, NX, BGXc, BGXn)                                         \
  {                                                                         \
    const unsigned short* Lb = lds[BU];                                     \
    const unsigned short* Ln = lds[NX];                                     \
    const int k1 = (((T) + 1 < NT) ? ((T) + 1) : ((T) + 1 - NT)) * 64;      \
    const int k2 = (((T) + 2 < NT) ? ((T) + 2) : ((T) + 2 - NT)) * 64;      \
    /* ph0 */                                                               \
    __builtin_amdgcn_s_barrier();                                           \
    RD_BG(bgY, Lb, 1);                                                      \
    SA(NX, 1, k1);                                                          \
    MM(0, 0, afA, BGXc);                                                    \
    /* ph1 */                                                               \
    __builtin_amdgcn_s_barrier();                                           \
    RD_AF(afB, Lb, 1);                                                      \
    SB(NX, 0, k1);                                                          \
    MM(0, 1, afA, bgY);                                                     \
    VMC_PH1();                                                              \
    /* ph2 */                                                               \
    __builtin_amdgcn_s_barrier();                                           \
    RD_AF(afA, Ln, 0);                                                      \
    SA(BU, 0, k2);                                                          \
    MM(1, 1, afB, bgY);                                                     \
    VMC_PH2();                                                              \
    /* ph3 */                                                               \
    __builtin_amdgcn_s_barrier();                                           \
    RD_BG(BGXn, Ln, 0);                                                     \
    SB(BU, 1, k2);                                                          \
    MM(1, 0, afB, BGXc);                                                    \
  }

  const int NT = K >> 6;  // always even here (16 or 32)

  // prologue: tile0 full + tile1's A_m0,B_n1; drain tile0; pre-read afA,bgX0
  SA(0, 0, 0); SA(0, 1, 0); SB(0, 0, 0); SB(0, 1, 0);
  SA(1, 0, 64); SB(1, 1, 64);
  VMC_PH1();  // leaves {A_m0(1), B_n1(1)} outstanding
  __builtin_amdgcn_s_barrier();
  RD_AF(afA, lds[0], 0);
  RD_BG(bgX0, lds[0], 0);

  for (int t = 0; t < NT; t += 2) {
    TILE(t, 0, 1, bgX0, bgX1);
    TILE(t + 1, 1, 0, bgX1, bgX0);
  }
  asm volatile("s_waitcnt vmcnt(0)" ::: "memory");

  // ---- epilogue ----
  if (EPI == 0) {
    unsigned short* C = (unsigned short*)Cv + (long long)z * sC;
#pragma unroll
    for (int tt = 0; tt < 8; ++tt)
#pragma unroll
      for (int u = 0; u < NBG; ++u)
#pragma unroll
        for (int j = 0; j < 4; ++j) {
          int row = m0 + wm * 128 + tt * 16 + q * 4 + j;
          int col = n0 + wn * BNW + u * 16 + rl;
          C[(long long)row * ldc + col] = f2bf(acc[tt][u][j] * alpha);
        }
  } else if (EPI == 1) {
    unsigned short* C = (unsigned short*)Cv + (long long)z * sC;
#pragma unroll
    for (int tt = 0; tt < 8; ++tt)
#pragma unroll
      for (int j = 0; j < 4; ++j) {
        int row = m0 + wm * 128 + tt * 16 + q * 4 + j;
        float sum = 0.f;
#pragma unroll
        for (int u = 0; u < NBG; ++u) {
          float e = __expf(acc[tt][u][j] * alpha);
          int col = n0 + wn * BNW + u * 16 + rl;
          C[(long long)row * ldc + col] = f2bf(e);
          sum += e;
        }
#pragma unroll
        for (int mk = 1; mk <= 8; mk <<= 1) sum += __shfl_xor(sum, mk);
        if (rl == 0) atomicAdd(&rowsum[z * rsz + row], sum);
      }
  } else {
    float* C = (float*)Cv + (long long)z * sC;
#pragma unroll
    for (int tt = 0; tt < 8; ++tt)
#pragma unroll
      for (int j = 0; j < 4; ++j) {
        int row = m0 + wm * 128 + tt * 16 + q * 4 + j;
        float inv = 1.0f / rowsum[z * rsz + row];
#pragma unroll
        for (int u = 0; u < NBG; ++u) {
          int col = n0 + wn * BNW + u * 16 + rl;
          C[(long long)row * ldc + col] = acc[tt][u][j] * inv;
        }
      }
  }
#undef SA
#undef SB
#undef RD_AF
#undef RD_BG
#undef MM
#undef VMC_PH1
#undef VMC_PH2
#undef TILE
}

// ---------------------------------------------------------------------------
// 128 x 128 NT bf16 GEMM (verified structure) -- used for V^T.
__global__ __launch_bounds__(256) void gemm_nt128(
    const unsigned short* __restrict__ A, const unsigned short* __restrict__ B,
    unsigned short* __restrict__ C, int K, int lda, int ldb, int ldc) {
  __shared__ unsigned short As[128 * 64];
  __shared__ unsigned short Bs[128 * 64];

  const int gx = gridDim.x, gy = gridDim.y;
  const int nwg = gx * gy;
  const int orig = blockIdx.y * gx + blockIdx.x;
  const int swz = (orig & 7) * (nwg >> 3) + (orig >> 3);
  const int bx = swz % gx;
  const int by = swz / gx;

  const int tid = threadIdx.x;
  const int lane = tid & 63;
  const int w = tid >> 6;
  const int wm = w >> 1, wn = w & 1;
  const int m0 = by * 128;
  const int n0 = bx * 128;

  int srow[4], scol[4];
#pragma unroll
  for (int i = 0; i < 4; ++i) {
    int p = w * 256 + i * 64 + lane;
    int r = p >> 3;
    srow[i] = r;
    scol[i] = ((p & 7) ^ (r & 7)) * 8;
  }

  const int q = lane >> 4, rl = lane & 15;
  int aoff[4][2], boff[4][2];
#pragma unroll
  for (int t = 0; t < 4; ++t)
#pragma unroll
    for (int ks = 0; ks < 2; ++ks) {
      int ra = wm * 64 + t * 16 + rl;
      int ca = ks * 4 + q;
      aoff[t][ks] = ra * 64 + ((ca ^ (ra & 7)) * 8);
      int rb = wn * 64 + t * 16 + rl;
      boff[t][ks] = rb * 64 + ((ca ^ (rb & 7)) * 8);
    }

  f32x4_t acc[4][4];
#pragma unroll
  for (int i = 0; i < 4; ++i)
#pragma unroll
    for (int j = 0; j < 4; ++j) acc[i][j] = (f32x4_t){0.f, 0.f, 0.f, 0.f};

  for (int k0 = 0; k0 < K; k0 += 64) {
    __syncthreads();
#pragma unroll
    for (int i = 0; i < 4; ++i) {
      GLOAD_LDS16(&A[(long long)(m0 + srow[i]) * lda + k0 + scol[i]],
                  &As[(w * 4 + i) * 512]);
      GLOAD_LDS16(&B[(long long)(n0 + srow[i]) * ldb + k0 + scol[i]],
                  &Bs[(w * 4 + i) * 512]);
    }
    __syncthreads();

#pragma unroll
    for (int ks = 0; ks < 2; ++ks) {
      bf16x8_t af[4], bgv[4];
#pragma unroll
      for (int t = 0; t < 4; ++t) af[t] = *(const bf16x8_t*)&As[aoff[t][ks]];
#pragma unroll
      for (int u = 0; u < 4; ++u) bgv[u] = *(const bf16x8_t*)&Bs[boff[u][ks]];
#pragma unroll
      for (int i = 0; i < 4; ++i)
#pragma unroll
        for (int j = 0; j < 4; ++j)
          acc[i][j] = __builtin_amdgcn_mfma_f32_16x16x32_bf16(
              af[i], bgv[j], acc[i][j], 0, 0, 0);
    }
  }

#pragma unroll
  for (int t = 0; t < 4; ++t)
#pragma unroll
    for (int u = 0; u < 4; ++u)
#pragma unroll
      for (int j = 0; j < 4; ++j) {
        int row = m0 + wm * 64 + t * 16 + q * 4 + j;
        int col = n0 + wn * 64 + u * 16 + rl;
        C[(long long)row * ldc + col] = f2bf(acc[t][u][j]);
      }
}

// ---------------------------------------------------------------------------
extern "C" void kernel_launch(void* const* d_in, const int* in_sizes, int n_in,
                              void* d_out, int out_size, void* d_ws,
                              size_t ws_size, hipStream_t stream) {
  const float* x = (const float*)d_in[0];
  const float* Wq = (const float*)d_in[1];
  const float* Wk = (const float*)d_in[2];
  const float* Wv = (const float*)d_in[3];
  float* out = (float*)d_out;

  // workspace (ushort elems)
  unsigned short* xb = (unsigned short*)d_ws;   // 8192x1024
  unsigned short* Wqk = xb + 8388608;           // 2048x1024 (Wq;Wk)
  unsigned short* Wvb = Wqk + 2097152;          // 1024x1024
  unsigned short* Cqk = Wvb + 1048576;          // 8192x2048 (Q|K)
  unsigned short* VTb = Cqk + 16777216;         // 1024x8192
  unsigned short* Scb = VTb + 8388608;          // 4x2048x2048 (exp scores)
  float* rowsumf = (float*)(Scb + 16777216);    // 8192 f32

  const dim3 blk(256);
  const dim3 blk512(512);

  cast_f32_bf16<<<4096, blk, 0, stream>>>(x, xb, 1048576);
  cast_w3<<<1540, blk, 0, stream>>>(Wq, Wk, Wv, Wqk, Wvb, rowsumf);

  // [Q|K] = x . Wqk^T : M=8192, N=2048, K=1024 -> 256 WGs
  gemm256p<0, 256><<<dim3(8, 32, 1), blk512, 0, stream>>>(
      xb, Wqk, Cqk, nullptr, 1024, 1024, 1024, 2048, 0, 0, 0, 1.0f, 0);

  // V^T = Wv . x^T [1024,8192]
  gemm_nt128<<<dim3(64, 8), blk, 0, stream>>>(Wvb, xb, VTb, 1024, 1024, 1024,
                                              8192);

  // E = exp(Q.K^T / 32) per batch -> bf16 + atomic rowsums; 256 WGs
  gemm256p<1, 256><<<dim3(8, 8, 4), blk512, 0, stream>>>(
      Cqk, Cqk + 1024, Scb, rowsumf, 1024, 2048, 2048, 2048,
      (long long)2048 * 2048, (long long)2048 * 2048, (long long)2048 * 2048,
      0.03125f, 2048);

  // out = (E . V) / rowsum : BN=128 -> grid (8,8,4) = 256 WGs
  gemm256p<2, 128><<<dim3(8, 8, 4), blk512, 0, stream>>>(
      Scb, VTb, out, rowsumf, 2048, 2048, 8192, 1024,
      (long long)2048 * 2048, 2048, (long long)2048 * 1024, 1.0f, 2048);
}

// Round 9
// 160.791 us; speedup vs baseline: 1.9165x; 1.9165x over previous
//
#include <hip/hip_runtime.h>
#include <hip/hip_bf16.h>

// Self-attention, MODEL_DIM=1024, BATCH=4, SEQ=2048.
// R9: R8's schedule (reordered stages, counted vmcnt with 3-4 phase
// issue-to-wait depth) with the R8 launch-arg corruption fixed:
// scores GEMM uses K=1024 and sA=sB=2048*2048 (was K=2048, 2048*1024).

typedef short bf16x8_t __attribute__((ext_vector_type(8)));
typedef float f32x4_t __attribute__((ext_vector_type(4)));
typedef unsigned short u16x8_t __attribute__((ext_vector_type(8)));

static __device__ __forceinline__ unsigned short f2bf(float f) {
  __hip_bfloat16 h = __float2bfloat16(f);
  return *reinterpret_cast<unsigned short*>(&h);
}

#define GLOAD_LDS16(gp, lp)                                            \
  __builtin_amdgcn_global_load_lds(                                    \
      (const __attribute__((address_space(1))) void*)(gp),             \
      (__attribute__((address_space(3))) void*)(lp), 16, 0, 0)

// ---------------------------------------------------------------------------
// One dispatch: x -> xb, Wq/Wk -> stacked Wqk, Wv -> Wvb, rowsum -> 0.
// Grid: 5636 blocks x 256 = 1442816 threads (1048576 + 393216 + 1024).
__global__ __launch_bounds__(256) void cast_all(
    const float* __restrict__ x, const float* __restrict__ Wq,
    const float* __restrict__ Wk, const float* __restrict__ Wv,
    unsigned short* __restrict__ xb, unsigned short* __restrict__ Wqk,
    unsigned short* __restrict__ Wvb, float* __restrict__ rowsum) {
  int i = blockIdx.x * 256 + threadIdx.x;
  const float* src;
  unsigned short* dst;
  int local;
  if (i < 1048576) {
    src = x; dst = xb; local = i;
  } else {
    int j = i - 1048576;
    int seg = j >> 17;
    if (seg >= 3) {
      int l = j - 393216;
      if (l < 1024) {
        float4 zz = {0.f, 0.f, 0.f, 0.f};
        ((float4*)rowsum)[l * 2] = zz;
        ((float4*)rowsum)[l * 2 + 1] = zz;
      }
      return;
    }
    local = j & 131071;
    src = (seg == 0) ? Wq : ((seg == 1) ? Wk : Wv);
    dst = (seg == 0) ? Wqk : ((seg == 1) ? (Wqk + 1048576) : Wvb);
  }
  float4 a = ((const float4*)src)[local * 2];
  float4 b = ((const float4*)src)[local * 2 + 1];
  u16x8_t o;
  o[0] = f2bf(a.x); o[1] = f2bf(a.y); o[2] = f2bf(a.z); o[3] = f2bf(a.w);
  o[4] = f2bf(b.x); o[5] = f2bf(b.y); o[6] = f2bf(b.z); o[7] = f2bf(b.w);
  ((u16x8_t*)dst)[local] = o;
}

// ---------------------------------------------------------------------------
// 256 x BN NT bf16 GEMM, BK=64, 512 threads = 8 waves (2M x 4N), 4 quadrant
// phases per K-tile, each {ds_read subtile; issue <=1 half-tile stage;
// barrier; lgkmcnt(0); 16 MFMA (setprio); barrier}. Reads consumed
// immediately (no cross-phase register liveness -- R7's spill lesson).
// Stage schedule (tile t): ph0 -> B_n0(t+1), ph1 -> A_m1(t+1),
//                          ph2 -> A_m0(t+2), ph3 -> B_n1(t+2).
// Counted waits: ph1 end vmcnt(8|6) completes A_m1(t) (issued 4 phases
// earlier); ph3 end vmcnt(6|5) completes A_m0(t+1),B_n1(t+1),B_n0(t+1)
// (issued >=3 phases earlier). Tail tiles drain with vmcnt(0).
// LDS chunk-XOR swizzled (phys = r*8 + (c8^(r&7))); bijective XCD swizzle.
// EPI 0: bf16(alpha*acc). 1: bf16(exp(alpha*acc)) + atomic rowsum.
// 2: f32 acc/rowsum[row].
template <int EPI, int BN>
__global__ __launch_bounds__(512, 2) void gemm256p(
    const unsigned short* __restrict__ A, const unsigned short* __restrict__ B,
    void* __restrict__ Cv, float* __restrict__ rowsum, int K, int lda,
    int ldb, int ldc, long long sA, long long sB, long long sC, float alpha,
    int rsz) {
  constexpr int NBG = BN / 64;  // bg frags per wave (4 / 2)
  constexpr int NH = NBG / 2;   // bg frags per phase (2 / 1)
  constexpr int BL = BN / 128;  // SB insts (2 / 1); SA insts = 2
  constexpr int BNW = BN / 4;   // wave n-extent (64 / 32)
  constexpr int ASZ = 256 * 64;
  constexpr int BSZ = BN * 64;

  __shared__ unsigned short lds[2][ASZ + BSZ];

  // T1: bijective XCD swizzle (nwg % 8 == 0 for all grids used)
  const int gx = gridDim.x, gy = gridDim.y;
  const int nwg = gx * gy * gridDim.z;
  const int orig = (blockIdx.z * gy + blockIdx.y) * gx + blockIdx.x;
  const int swz = (orig & 7) * (nwg >> 3) + (orig >> 3);
  const int bx = swz % gx;
  const int tmp = swz / gx;
  const int by = tmp % gy;
  const int z = tmp / gy;

  const int tid = threadIdx.x;
  const int lane = tid & 63;
  const int w = tid >> 6;
  const int wm = w >> 2, wn = w & 3;
  const int m0 = by * 256, n0 = bx * BN;

  A += (long long)z * sA;
  B += (long long)z * sB;

  // staging index tables (chunk l holds k-chunk (l&7)^(row&7))
  int sta_row[2][2], sta_col[2][2], sta_lds[2][2];
#pragma unroll
  for (int mh = 0; mh < 2; ++mh)
#pragma unroll
    for (int i = 0; i < 2; ++i) {
      int j = w * 2 + i;
      int l0 = (j >> 3) * 1024 + mh * 512 + (j & 7) * 64;
      int lf = l0 + lane;
      int R = lf >> 3;
      sta_row[mh][i] = R;
      sta_col[mh][i] = ((lf & 7) ^ (R & 7)) * 8;
      sta_lds[mh][i] = l0 * 8;
    }
  int stb_row[2][BL], stb_col[2][BL], stb_lds[2][BL];
#pragma unroll
  for (int nh = 0; nh < 2; ++nh)
#pragma unroll
    for (int i = 0; i < BL; ++i) {
      int l0;
      if (BL == 2) {
        int j = w * 2 + i;
        l0 = (j >> 2) * 512 + nh * 256 + (j & 3) * 64;
      } else {
        int j = w;
        l0 = (j >> 1) * 256 + nh * 128 + (j & 1) * 64;
      }
      int lf = l0 + lane;
      int R = lf >> 3;
      stb_row[nh][i] = R;
      stb_col[nh][i] = ((lf & 7) ^ (R & 7)) * 8;
      stb_lds[nh][i] = ASZ + l0 * 8;
    }

  // ds_read element offsets (K-invariant)
  const int q = lane >> 4, rl = lane & 15;
  int aoff[8][2], boff[NBG][2];
#pragma unroll
  for (int tt = 0; tt < 8; ++tt)
#pragma unroll
    for (int ks = 0; ks < 2; ++ks) {
      int ra = wm * 128 + tt * 16 + rl;
      aoff[tt][ks] = ra * 64 + (((ks * 4 + q) ^ (ra & 7)) * 8);
    }
#pragma unroll
  for (int u = 0; u < NBG; ++u)
#pragma unroll
    for (int ks = 0; ks < 2; ++ks) {
      int rb = wn * BNW + u * 16 + rl;
      boff[u][ks] = ASZ + rb * 64 + (((ks * 4 + q) ^ (rb & 7)) * 8);
    }

  f32x4_t acc[8][NBG];
#pragma unroll
  for (int i = 0; i < 8; ++i)
#pragma unroll
    for (int j = 0; j < NBG; ++j) acc[i][j] = (f32x4_t){0.f, 0.f, 0.f, 0.f};

#define SA(BUFI, MH, K0)                                                    \
  {                                                                         \
    _Pragma("unroll") for (int i_ = 0; i_ < 2; ++i_)                        \
        GLOAD_LDS16(&A[(long long)(m0 + sta_row[MH][i_]) * lda + (K0) +     \
                       sta_col[MH][i_]],                                    \
                    &lds[BUFI][sta_lds[MH][i_]]);                           \
  }
#define SB(BUFI, NH_, K0)                                                   \
  {                                                                         \
    _Pragma("unroll") for (int i_ = 0; i_ < BL; ++i_)                       \
        GLOAD_LDS16(&B[(long long)(n0 + stb_row[NH_][i_]) * ldb + (K0) +    \
                       stb_col[NH_][i_]],                                   \
                    &lds[BUFI][stb_lds[NH_][i_]]);                          \
  }
#define LDAF(MH)                                                            \
  _Pragma("unroll") for (int i_ = 0; i_ < 4; ++i_)                          \
  _Pragma("unroll") for (int ks_ = 0; ks_ < 2; ++ks_)                       \
      af[i_][ks_] = *(const bf16x8_t*)&L[aoff[(MH)*4 + i_][ks_]];
#define LDBG(NH_)                                                           \
  _Pragma("unroll") for (int j_ = 0; j_ < NH; ++j_)                         \
  _Pragma("unroll") for (int ks_ = 0; ks_ < 2; ++ks_)                       \
      bg[j_][ks_] = *(const bf16x8_t*)&L[boff[(NH_)*NH + j_][ks_]];
#define PH_MFMA(MH, NH_)                                                    \
  __builtin_amdgcn_s_barrier();                                             \
  asm volatile("s_waitcnt lgkmcnt(0)" ::: "memory");                        \
  __builtin_amdgcn_sched_barrier(0);                                        \
  __builtin_amdgcn_s_setprio(1);                                            \
  _Pragma("unroll") for (int ks_ = 0; ks_ < 2; ++ks_)                       \
  _Pragma("unroll") for (int i_ = 0; i_ < 4; ++i_)                          \
  _Pragma("unroll") for (int j_ = 0; j_ < NH; ++j_)                         \
      acc[(MH)*4 + i_][(NH_)*NH + j_] =                                     \
          __builtin_amdgcn_mfma_f32_16x16x32_bf16(                          \
              af[i_][ks_], bg[j_][ks_], acc[(MH)*4 + i_][(NH_)*NH + j_],    \
              0, 0, 0);                                                     \
  __builtin_amdgcn_s_setprio(0);                                            \
  __builtin_amdgcn_sched_barrier(0);                                        \
  __builtin_amdgcn_s_barrier();                                             \
  __builtin_amdgcn_sched_barrier(0);

  // counted waits (instruction counts; literal immediates)
#define VMC_A()                                                             \
  if constexpr (BL == 2) {                                                  \
    asm volatile("s_waitcnt vmcnt(8)" ::: "memory");                        \
  } else {                                                                  \
    asm volatile("s_waitcnt vmcnt(6)" ::: "memory");                        \
  }                                                                         \
  __builtin_amdgcn_sched_barrier(0);
#define VMC_B()                                                             \
  if constexpr (BL == 2) {                                                  \
    asm volatile("s_waitcnt vmcnt(6)" ::: "memory");                        \
  } else {                                                                  \
    asm volatile("s_waitcnt vmcnt(5)" ::: "memory");                        \
  }                                                                         \
  __builtin_amdgcn_sched_barrier(0);
#define VMC_0()                                                             \
  asm volatile("s_waitcnt vmcnt(0)" ::: "memory");                          \
  __builtin_amdgcn_sched_barrier(0);

#define TILE(T, BU, NX)                                                     \
  {                                                                         \
    const unsigned short* L = lds[BU];                                      \
    const int k1 = ((T) + 1) * 64;                                          \
    const int k2 = ((T) + 2) * 64;                                          \
    const bool p1 = ((T) + 1 < NT), p2 = ((T) + 2 < NT);                    \
    bf16x8_t af[4][2], bg[NH][2];                                           \
    /* ph0 (m0,n0) */                                                       \
    LDAF(0);                                                                \
    LDBG(0);                                                                \
    if (p1) SB(NX, 0, k1);                                                  \
    PH_MFMA(0, 0);                                                          \
    /* ph1 (m0,n1) */                                                       \
    LDBG(1);                                                                \
    if (p1) SA(NX, 1, k1);                                                  \
    if (p2) { VMC_A(); } else { VMC_0(); }                                  \
    PH_MFMA(0, 1);                                                          \
    /* ph2 (m1,n1) */                                                       \
    LDAF(1);                                                                \
    if (p2) SA(BU, 0, k2);                                                  \
    PH_MFMA(1, 1);                                                          \
    /* ph3 (m1,n0) */                                                       \
    LDBG(0);                                                                \
    if (p2) { SB(BU, 1, k2); VMC_B(); } else { VMC_0(); }                   \
    PH_MFMA(1, 0);                                                          \
  }

  const int NT = K >> 6;  // even (16 or 32)

  // prologue (issue order fixed): A_m0(0), B_n0(0), B_n1(0), A_m1(0),
  // A_m0(1), B_n1(1); complete oldest 3 stages -> steady-state invariant.
  SA(0, 0, 0); SB(0, 0, 0); SB(0, 1, 0); SA(0, 1, 0);
  SA(1, 0, 64); SB(1, 1, 64);
  VMC_B();
  __builtin_amdgcn_s_barrier();
  __builtin_amdgcn_sched_barrier(0);

  for (int t = 0; t < NT; t += 2) {
    TILE(t, 0, 1);
    TILE(t + 1, 1, 0);
  }

  // ---- epilogue ----
  if (EPI == 0) {
    unsigned short* C = (unsigned short*)Cv + (long long)z * sC;
#pragma unroll
    for (int tt = 0; tt < 8; ++tt)
#pragma unroll
      for (int u = 0; u < NBG; ++u)
#pragma unroll
        for (int j = 0; j < 4; ++j) {
          int row = m0 + wm * 128 + tt * 16 + q * 4 + j;
          int col = n0 + wn * BNW + u * 16 + rl;
          C[(long long)row * ldc + col] = f2bf(acc[tt][u][j] * alpha);
        }
  } else if (EPI == 1) {
    unsigned short* C = (unsigned short*)Cv + (long long)z * sC;
#pragma unroll
    for (int tt = 0; tt < 8; ++tt)
#pragma unroll
      for (int j = 0; j < 4; ++j) {
        int row = m0 + wm * 128 + tt * 16 + q * 4 + j;
        float sum = 0.f;
#pragma unroll
        for (int u = 0; u < NBG; ++u) {
          float e = __expf(acc[tt][u][j] * alpha);
          int col = n0 + wn * BNW + u * 16 + rl;
          C[(long long)row * ldc + col] = f2bf(e);
          sum += e;
        }
#pragma unroll
        for (int mk = 1; mk <= 8; mk <<= 1) sum += __shfl_xor(sum, mk);
        if (rl == 0) atomicAdd(&rowsum[z * rsz + row], sum);
      }
  } else {
    float* C = (float*)Cv + (long long)z * sC;
#pragma unroll
    for (int tt = 0; tt < 8; ++tt)
#pragma unroll
      for (int j = 0; j < 4; ++j) {
        int row = m0 + wm * 128 + tt * 16 + q * 4 + j;
        float inv = 1.0f / rowsum[z * rsz + row];
#pragma unroll
        for (int u = 0; u < NBG; ++u) {
          int col = n0 + wn * BNW + u * 16 + rl;
          C[(long long)row * ldc + col] = acc[tt][u][j] * inv;
        }
      }
  }
#undef SA
#undef SB
#undef LDAF
#undef LDBG
#undef PH_MFMA
#undef VMC_A
#undef VMC_B
#undef VMC_0
#undef TILE
}

// ---------------------------------------------------------------------------
// 128 x 128 NT bf16 GEMM (verified structure) -- used for V^T.
__global__ __launch_bounds__(256) void gemm_nt128(
    const unsigned short* __restrict__ A, const unsigned short* __restrict__ B,
    unsigned short* __restrict__ C, int K, int lda, int ldb, int ldc) {
  __shared__ unsigned short As[128 * 64];
  __shared__ unsigned short Bs[128 * 64];

  const int gx = gridDim.x, gy = gridDim.y;
  const int nwg = gx * gy;
  const int orig = blockIdx.y * gx + blockIdx.x;
  const int swz = (orig & 7) * (nwg >> 3) + (orig >> 3);
  const int bx = swz % gx;
  const int by = swz / gx;

  const int tid = threadIdx.x;
  const int lane = tid & 63;
  const int w = tid >> 6;
  const int wm = w >> 1, wn = w & 1;
  const int m0 = by * 128;
  const int n0 = bx * 128;

  int srow[4], scol[4];
#pragma unroll
  for (int i = 0; i < 4; ++i) {
    int p = w * 256 + i * 64 + lane;
    int r = p >> 3;
    srow[i] = r;
    scol[i] = ((p & 7) ^ (r & 7)) * 8;
  }

  const int q = lane >> 4, rl = lane & 15;
  int aoff[4][2], boff[4][2];
#pragma unroll
  for (int t = 0; t < 4; ++t)
#pragma unroll
    for (int ks = 0; ks < 2; ++ks) {
      int ra = wm * 64 + t * 16 + rl;
      int ca = ks * 4 + q;
      aoff[t][ks] = ra * 64 + ((ca ^ (ra & 7)) * 8);
      int rb = wn * 64 + t * 16 + rl;
      boff[t][ks] = rb * 64 + ((ca ^ (rb & 7)) * 8);
    }

  f32x4_t acc[4][4];
#pragma unroll
  for (int i = 0; i < 4; ++i)
#pragma unroll
    for (int j = 0; j < 4; ++j) acc[i][j] = (f32x4_t){0.f, 0.f, 0.f, 0.f};

  for (int k0 = 0; k0 < K; k0 += 64) {
    __syncthreads();
#pragma unroll
    for (int i = 0; i < 4; ++i) {
      GLOAD_LDS16(&A[(long long)(m0 + srow[i]) * lda + k0 + scol[i]],
                  &As[(w * 4 + i) * 512]);
      GLOAD_LDS16(&B[(long long)(n0 + srow[i]) * ldb + k0 + scol[i]],
                  &Bs[(w * 4 + i) * 512]);
    }
    __syncthreads();

#pragma unroll
    for (int ks = 0; ks < 2; ++ks) {
      bf16x8_t af[4], bgv[4];
#pragma unroll
      for (int t = 0; t < 4; ++t) af[t] = *(const bf16x8_t*)&As[aoff[t][ks]];
#pragma unroll
      for (int u = 0; u < 4; ++u) bgv[u] = *(const bf16x8_t*)&Bs[boff[u][ks]];
#pragma unroll
      for (int i = 0; i < 4; ++i)
#pragma unroll
        for (int j = 0; j < 4; ++j)
          acc[i][j] = __builtin_amdgcn_mfma_f32_16x16x32_bf16(
              af[i], bgv[j], acc[i][j], 0, 0, 0);
    }
  }

#pragma unroll
  for (int t = 0; t < 4; ++t)
#pragma unroll
    for (int u = 0; u < 4; ++u)
#pragma unroll
      for (int j = 0; j < 4; ++j) {
        int row = m0 + wm * 64 + t * 16 + q * 4 + j;
        int col = n0 + wn * 64 + u * 16 + rl;
        C[(long long)row * ldc + col] = f2bf(acc[t][u][j]);
      }
}

// ---------------------------------------------------------------------------
extern "C" void kernel_launch(void* const* d_in, const int* in_sizes, int n_in,
                              void* d_out, int out_size, void* d_ws,
                              size_t ws_size, hipStream_t stream) {
  const float* x = (const float*)d_in[0];
  const float* Wq = (const float*)d_in[1];
  const float* Wk = (const float*)d_in[2];
  const float* Wv = (const float*)d_in[3];
  float* out = (float*)d_out;

  // workspace (ushort elems)
  unsigned short* xb = (unsigned short*)d_ws;   // 8192x1024
  unsigned short* Wqk = xb + 8388608;           // 2048x1024 (Wq;Wk)
  unsigned short* Wvb = Wqk + 2097152;          // 1024x1024
  unsigned short* Cqk = Wvb + 1048576;          // 8192x2048 (Q|K)
  unsigned short* VTb = Cqk + 16777216;         // 1024x8192
  unsigned short* Scb = VTb + 8388608;          // 4x2048x2048 (exp scores)
  float* rowsumf = (float*)(Scb + 16777216);    // 8192 f32

  const dim3 blk(256);
  const dim3 blk512(512);

  cast_all<<<5636, blk, 0, stream>>>(x, Wq, Wk, Wv, xb, Wqk, Wvb, rowsumf);

  // [Q|K] = x . Wqk^T : M=8192, N=2048, K=1024 -> 256 WGs
  gemm256p<0, 256><<<dim3(8, 32, 1), blk512, 0, stream>>>(
      xb, Wqk, Cqk, nullptr, 1024, 1024, 1024, 2048, 0, 0, 0, 1.0f, 0);

  // V^T = Wv . x^T [1024,8192]
  gemm_nt128<<<dim3(64, 8), blk, 0, stream>>>(Wvb, xb, VTb, 1024, 1024, 1024,
                                              8192);

  // E = exp(Q.K^T / 32) per batch -> bf16 + atomic rowsums; 256 WGs
  // K=1024 (model dim), per-batch stride 2048 rows x lda 2048.
  gemm256p<1, 256><<<dim3(8, 8, 4), blk512, 0, stream>>>(
      Cqk, Cqk + 1024, Scb, rowsumf, 1024, 2048, 2048, 2048,
      (long long)2048 * 2048, (long long)2048 * 2048,
      (long long)2048 * 2048, 0.03125f, 2048);

  // out = (E . V) / rowsum : BN=128 -> grid (8,8,4) = 256 WGs
  gemm256p<2, 128><<<dim3(8, 8, 4), blk512, 0, stream>>>(
      Scb, VTb, out, rowsumf, 2048, 2048, 8192, 1024,
      (long long)2048 * 2048, 2048, (long long)2048 * 1024, 1.0f, 2048);
}